// Round 10
// baseline (359.805 us; speedup 1.0000x reference)
//
#include <hip/hip_runtime.h>
#include <math.h>

#define L_  12
#define B_  32
#define H_  12
#define N1_ 197
#define D_  768
#define R_  19
#define M_TOK (B_ * N1_)               // 6304
#define NN (N1_ * N1_)                 // 38809

#define K1_FULL_ROWS  69344            // 11 layers * 32 b * 197 rows
#define K1_ROWS       69376            // + 32 layer-11 row-0 rows
#define K1_BLOCKS     (K1_ROWS / 4)    // 17344
#define PACK_ROWS     (M_TOK + 2304)   // x rows + [k;v;q] weight rows = 8608
#define PACK_BLOCKS   ((PACK_ROWS * 12 + 255) / 256)   // 404
#define QKV_TILES     900              // 50 x 18 (M=6304, N=2304, all tokens)
#define MEGA_BLOCKS   (QKV_TILES + K1_BLOCKS)

typedef __attribute__((ext_vector_type(8))) _Float16 f16x8;
typedef __attribute__((ext_vector_type(4))) float f32x4;

__device__ __forceinline__ f32x4 ld4u(const float* p) {
  f32x4 r; __builtin_memcpy(&r, p, 16); return r;
}
__device__ __forceinline__ void st4u(float* p, f32x4 v) {
  __builtin_memcpy(p, &v, 16);
}

typedef const __attribute__((address_space(1))) void* as1_vp;
typedef __attribute__((address_space(3))) void* as3_vp;
__device__ __forceinline__ void gl_lds16(const void* g, void* s) {
  __builtin_amdgcn_global_load_lds((as1_vp)g, (as3_vp)s, 16, 0, 0);
}

// ---------------------------------------------------------------------------
// PACK: x and [k_w; v_w; q_w] -> fp16 [row][12][64 fp16 = 128B], coalesced.
// Runs first (GEMM input). 404 blocks, ~10 us.
// ---------------------------------------------------------------------------
__global__ __launch_bounds__(256) void pack_fp16(const float* __restrict__ x,
                                                 const float* __restrict__ k_w,
                                                 const float* __restrict__ v_w,
                                                 const float* __restrict__ q_w,
                                                 ushort* __restrict__ xpack,
                                                 ushort* __restrict__ wpack) {
  int t = blockIdx.x * 256 + threadIdx.x;
  if (t >= PACK_ROWS * 12) return;
  int row = t / 12, kb = t - row * 12;
  const float* src;
  ushort* dst;
  if (row < M_TOK) {
    src = x + (size_t)row * D_;
    dst = xpack + (size_t)row * 768;
  } else {
    int wr = row - M_TOK;                 // 0..2303
    int g = wr / 768, rl = wr - g * 768;
    const float* wsrc = (g == 0) ? k_w : (g == 1) ? v_w : q_w;
    src = wsrc + (size_t)rl * D_;
    dst = wpack + (size_t)wr * 768;
  }
  src += kb * 64;
  dst += kb * 64;
#pragma unroll
  for (int u = 0; u < 8; ++u) {
    float4 f = *(const float4*)(src + u * 8);
    float4 g = *(const float4*)(src + u * 8 + 4);
    f16x8 h;
    h[0] = (_Float16)f.x; h[1] = (_Float16)f.y;
    h[2] = (_Float16)f.z; h[3] = (_Float16)f.w;
    h[4] = (_Float16)g.x; h[5] = (_Float16)g.y;
    h[6] = (_Float16)g.z; h[7] = (_Float16)g.w;
    *(f16x8*)(dst + u * 8) = h;
  }
}

// ---------------------------------------------------------------------------
// MEGA: blocks [0, 900) = fp16 QKV GEMM (all tokens, N=2304; lean: gl_lds
// staging, 1 MFMA pass, 32 KB LDS -> 5 blocks/CU) front-loaded so they
// dispatch first; blocks [900, +17344) = k1 head-mean+normalize (R6-proven,
// one wave per row, vectorized). k1 at 20 waves/CU still has ~190 KB loads
// in flight >> the ~9 KB needed for per-CU BW, so the LDS union should not
// throttle it (R4's killers -- VALU staging, 3-pass MFMA, 40 KB -- removed).
// ---------------------------------------------------------------------------
__global__ __launch_bounds__(256) void mega_gemm_k1(const ushort* __restrict__ xpack,
                                                    const ushort* __restrict__ wpack,
                                                    float* __restrict__ qkv,
                                                    const float* __restrict__ attn,
                                                    float* __restrict__ P,
                                                    float* __restrict__ dvec) {
  __shared__ __attribute__((aligned(16))) ushort As[128 * 64];
  __shared__ __attribute__((aligned(16))) ushort Bs[128 * 64];
  int bid = blockIdx.x;
  if (bid < QKV_TILES) {
    int tid = threadIdx.x, lane = tid & 63, wid = tid >> 6;
    int wr = wid >> 1, wc = wid & 1;
    int lr = lane & 15, lk = lane >> 4;
    int bm = bid % 50, bn = bid / 50;          // 50 x 18

    const ushort* asrc[4];
    const ushort* bsrc[4];
    ushort* adst[4];
    ushort* bdst[4];
    int lrow = lane >> 3, cpr = lane & 7;
#pragma unroll
    for (int i = 0; i < 4; ++i) {
      int r_loc = wid * 32 + i * 8 + lrow;
      int c     = cpr ^ (r_loc & 7);
      int ga    = bm * 128 + r_loc; if (ga >= M_TOK) ga = M_TOK - 1;
      asrc[i] = xpack + (size_t)ga * 768 + c * 8;
      bsrc[i] = wpack + (size_t)(bn * 128 + r_loc) * 768 + c * 8;
      adst[i] = &As[(wid * 32 + i * 8) * 64];
      bdst[i] = &Bs[(wid * 32 + i * 8) * 64];
    }

    int o0 = (lk ^ (lr & 7)) * 8;      // slice 0 (k 0..31)
    int o1 = o0 ^ 32;                  // slice 1 (k 32..63)

    f32x4 acc[4][4] = {};

#pragma unroll
    for (int i = 0; i < 4; ++i) { gl_lds16(asrc[i], adst[i]); gl_lds16(bsrc[i], bdst[i]); }

    for (int kb = 0; kb < 12; ++kb) {
      __syncthreads();
      f16x8 af0[4], af1[4], bf0[4], bf1[4];
#pragma unroll
      for (int m = 0; m < 4; ++m) {
        const ushort* rp = &As[(wr * 64 + m * 16 + lr) * 64];
        af0[m] = *(const f16x8*)(rp + o0);
        af1[m] = *(const f16x8*)(rp + o1);
      }
#pragma unroll
      for (int n = 0; n < 4; ++n) {
        const ushort* rp = &Bs[(wc * 64 + n * 16 + lr) * 64];
        bf0[n] = *(const f16x8*)(rp + o0);
        bf1[n] = *(const f16x8*)(rp + o1);
      }
      __syncthreads();
      if (kb < 11) {
#pragma unroll
        for (int i = 0; i < 4; ++i) {
          gl_lds16(asrc[i] + (kb + 1) * 64, adst[i]);
          gl_lds16(bsrc[i] + (kb + 1) * 64, bdst[i]);
        }
      }
#pragma unroll
      for (int m = 0; m < 4; ++m)
#pragma unroll
        for (int n = 0; n < 4; ++n) {
          acc[m][n] = __builtin_amdgcn_mfma_f32_16x16x32_f16(af0[m], bf0[n], acc[m][n], 0, 0, 0);
          acc[m][n] = __builtin_amdgcn_mfma_f32_16x16x32_f16(af1[m], bf1[n], acc[m][n], 0, 0, 0);
        }
    }

#pragma unroll
    for (int m = 0; m < 4; ++m) {
      int row0 = bm * 128 + wr * 64 + m * 16 + (lane >> 4) * 4;
#pragma unroll
      for (int i = 0; i < 4; ++i) {
        int row = row0 + i;
        if (row < M_TOK) {
#pragma unroll
          for (int n = 0; n < 4; ++n) {
            int col = bn * 128 + wc * 64 + n * 16 + lr;
            qkv[(size_t)row * 2304 + col] = acc[m][n][i];
          }
        }
      }
    }
  } else {
    // ----- k1: head-mean + normalize (R6-proven path) -----
    int wid = threadIdx.x >> 6;
    int t   = threadIdx.x & 63;
    int row_id = (bid - QKV_TILES) * 4 + wid;
    int l, b, i;
    if (row_id < K1_FULL_ROWS) {
      l = row_id / 6304;
      int rem = row_id - l * 6304;
      b = rem / 197;
      i = rem - b * 197;
    } else {
      l = 11; b = row_id - K1_FULL_ROWS; i = 0;
    }
    int lb   = l * B_ + b;
    int prow = lb * N1_ + i;
    const float* base = attn + (size_t)lb * (H_ * NN) + (size_t)i * N1_;
    f32x4 acc = {0.f, 0.f, 0.f, 0.f};
    if (t < 49) {
      const float* p = base + 4 * t;
#pragma unroll
      for (int h = 0; h < H_; ++h) acc += ld4u(p + (size_t)h * NN);
    } else if (t == 49) {
      const float* p = base + 196;
#pragma unroll
      for (int h = 0; h < H_; ++h) acc.x += p[(size_t)h * NN];
    }
    float s = (acc.x + acc.y) + (acc.z + acc.w);
#pragma unroll
    for (int o = 32; o; o >>= 1) s += __shfl_xor(s, o);
    float inv = 1.f / (s + 12.f);
    float* Pr = P + (size_t)prow * N1_;
    if (t < 49)       st4u(Pr + 4 * t, acc * inv);
    else if (t == 49) Pr[196] = acc.x * inv;
    if (t == 0) dvec[prow] = 12.f * inv;
  }
}

// ---------------------------------------------------------------------------
// K2: rollout chain (row 0) + top-19. 1024 threads, 4-way i-split, register
// PREFETCH of next layer's P columns (loads are v-independent -> L3 latency
// hidden under the current layer's FMAs + barrier).
// ---------------------------------------------------------------------------
__global__ __launch_bounds__(1024) void k2_chain_topk(const float* __restrict__ P,
                                                      const float* __restrict__ dvec,
                                                      int* __restrict__ gidx) {
  int b = blockIdx.x;
  __shared__ float v[N1_];
  __shared__ float part[4][N1_];
  int t = threadIdx.x, quar = t >> 8, j = t & 255;
  int ibeg = (quar * N1_) / 4;              // 0,49,98,147
  bool last50 = (quar == 3);                // iend-ibeg = 49,49,49,50

  if (t < N1_) {
    const float* Pr = P + ((size_t)(11 * B_ + b) * N1_) * N1_;
    v[t] = Pr[t] + (t == 0 ? dvec[(11 * B_ + b) * N1_] : 0.f);
  }

  float cur[50], nxt[50];
  if (j < N1_) {
    const float* Pc = P + ((size_t)(10 * B_ + b) * N1_) * N1_ + j;
#pragma unroll
    for (int u = 0; u < 50; ++u) {
      int i = ibeg + u; if (i > 196) i = 196;
      cur[u] = Pc[(size_t)i * N1_];
    }
  }
  __syncthreads();

  for (int l = 10; l >= 0; --l) {
    if (l > 0 && j < N1_) {                 // prefetch layer l-1
      const float* Pc = P + ((size_t)((l - 1) * B_ + b) * N1_) * N1_ + j;
#pragma unroll
      for (int u = 0; u < 50; ++u) {
        int i = ibeg + u; if (i > 196) i = 196;
        nxt[u] = Pc[(size_t)i * N1_];
      }
    }
    if (j < N1_) {
      float a0 = 0.f, a1 = 0.f, a2 = 0.f, a3 = 0.f;
#pragma unroll
      for (int u = 0; u < 48; u += 4) {
        a0 += v[ibeg + u]     * cur[u];
        a1 += v[ibeg + u + 1] * cur[u + 1];
        a2 += v[ibeg + u + 2] * cur[u + 2];
        a3 += v[ibeg + u + 3] * cur[u + 3];
      }
      a0 += v[ibeg + 48] * cur[48];
      if (last50) a1 += v[ibeg + 49] * cur[49];
      float s = (a0 + a1) + (a2 + a3);
      if (quar == 0) s += v[j] * dvec[(l * B_ + b) * N1_ + j];   // diagonal
      part[quar][j] = s;
    }
    __syncthreads();
    if (t < N1_) v[t] = (part[0][t] + part[1][t]) + (part[2][t] + part[3][t]);
    __syncthreads();
#pragma unroll
    for (int u = 0; u < 50; ++u) cur[u] = nxt[u];
  }

  // top-19 over v[1..196]; jax tie-break: value desc, index asc
  if (t < 64) {
    float val[4];
    int   idx[4];
#pragma unroll
    for (int c = 0; c < 4; ++c) {
      int n = t + c * 64;
      bool ok = (n < N1_ - 1);
      val[c] = ok ? v[n + 1] : -1e30f;
      idx[c] = ok ? n : (1 << 20);
    }
    for (int r = 0; r < R_; ++r) {
      float bv = val[0];
      int   bi = idx[0];
#pragma unroll
      for (int c = 1; c < 4; ++c)
        if (val[c] > bv || (val[c] == bv && idx[c] < bi)) { bv = val[c]; bi = idx[c]; }
#pragma unroll
      for (int o = 32; o; o >>= 1) {
        float ov = __shfl_xor(bv, o);
        int   oi = __shfl_xor(bi, o);
        if (ov > bv || (ov == bv && oi < bi)) { bv = ov; bi = oi; }
      }
      if (t == 0) gidx[b * R_ + r] = b * N1_ + bi + 1;
#pragma unroll
      for (int c = 0; c < 4; ++c)
        if (idx[c] == bi) val[c] = -1e30f;
    }
  }
}

// ---------------------------------------------------------------------------
// K5: per-(b,h) attention (f32). K/V/Q from 2304-wide qkv; q gathered by
// gidx (projection commutes with the gather). (R7-proven variant)
// ---------------------------------------------------------------------------
__global__ __launch_bounds__(256) void k5_attn(const float* __restrict__ qkv,
                                               const int* __restrict__ gidx,
                                               float* __restrict__ ctx) {
  int bh = blockIdx.x;
  int b = bh / H_, h = bh % H_;
  __shared__ float ks[N1_][68];
  __shared__ float qs[R_][64];
  __shared__ float sc[R_][200];
  __shared__ float rsum[R_];
  int t = threadIdx.x;
  int lane = t & 63, wid = t >> 6;

  const float* kbase = qkv + (size_t)(b * N1_) * 2304 + h * 64;
  for (int n = wid; n < N1_; n += 4)
    ks[n][lane] = kbase[(size_t)n * 2304 + lane];
  for (int e = t; e < R_ * 64; e += 256) {
    int r = e >> 6, d = e & 63;
    int grow = gidx[b * R_ + r];
    qs[r][d] = qkv[(size_t)grow * 2304 + 1536 + h * 64 + d];
  }
  __syncthreads();

  if (t < N1_) {
    float accr[R_];
#pragma unroll
    for (int r = 0; r < R_; ++r) accr[r] = 0.f;
#pragma unroll
    for (int d0 = 0; d0 < 4; ++d0) {
      float4 k0 = *(const float4*)&ks[t][d0 * 16 + 0];
      float4 k1 = *(const float4*)&ks[t][d0 * 16 + 4];
      float4 k2 = *(const float4*)&ks[t][d0 * 16 + 8];
      float4 k3 = *(const float4*)&ks[t][d0 * 16 + 12];
#pragma unroll
      for (int r = 0; r < R_; ++r) {
        float4 q0 = *(const float4*)&qs[r][d0 * 16 + 0];
        float4 q1 = *(const float4*)&qs[r][d0 * 16 + 4];
        float4 q2 = *(const float4*)&qs[r][d0 * 16 + 8];
        float4 q3 = *(const float4*)&qs[r][d0 * 16 + 12];
        accr[r] += k0.x * q0.x + k0.y * q0.y + k0.z * q0.z + k0.w * q0.w
                 + k1.x * q1.x + k1.y * q1.y + k1.z * q1.z + k1.w * q1.w
                 + k2.x * q2.x + k2.y * q2.y + k2.z * q2.z + k2.w * q2.w
                 + k3.x * q3.x + k3.y * q3.y + k3.z * q3.z + k3.w * q3.w;
      }
    }
#pragma unroll
    for (int r = 0; r < R_; ++r) sc[r][t] = accr[r] * 0.125f;
  }
  __syncthreads();

  for (int r = wid; r < R_; r += 4) {
    float x0 = sc[r][lane];
    float x1 = sc[r][lane + 64];
    float x2 = sc[r][lane + 128];
    bool ok3 = (lane + 192 < N1_);
    float x3 = ok3 ? sc[r][lane + 192] : -1e30f;
    float m = fmaxf(fmaxf(x0, x1), fmaxf(x2, x3));
#pragma unroll
    for (int o = 32; o; o >>= 1) m = fmaxf(m, __shfl_xor(m, o));
    float e0 = expf(x0 - m), e1 = expf(x1 - m), e2 = expf(x2 - m);
    float e3 = ok3 ? expf(x3 - m) : 0.f;
    float s = e0 + e1 + e2 + e3;
#pragma unroll
    for (int o = 32; o; o >>= 1) s += __shfl_xor(s, o);
    sc[r][lane] = e0; sc[r][lane + 64] = e1; sc[r][lane + 128] = e2;
    if (ok3) sc[r][lane + 192] = e3;
    if (lane == 0) rsum[r] = s;
  }
  __syncthreads();

  const float* vb = qkv + (size_t)(b * N1_) * 2304 + 768 + h * 64 + lane;
  int r0 = wid, r1 = wid + 4, r2 = wid + 8, r3 = wid + 12, r4 = wid + 16;
  bool has4 = (r4 < R_);
  float a0 = 0.f, a1 = 0.f, a2 = 0.f, a3 = 0.f, a4 = 0.f;
#pragma unroll 4
  for (int n = 0; n < N1_; ++n) {
    float vv = vb[(size_t)n * 2304];
    a0 += sc[r0][n] * vv;
    a1 += sc[r1][n] * vv;
    a2 += sc[r2][n] * vv;
    a3 += sc[r3][n] * vv;
    if (has4) a4 += sc[r4][n] * vv;
  }
  float* cb = ctx + (size_t)(b * R_) * D_ + h * 64 + lane;
  cb[(size_t)r0 * D_] = a0 / rsum[r0];
  cb[(size_t)r1 * D_] = a1 / rsum[r1];
  cb[(size_t)r2 * D_] = a2 / rsum[r2];
  cb[(size_t)r3 * D_] = a3 / rsum[r3];
  if (has4) cb[(size_t)r4 * D_] = a4 / rsum[r4];
}

// ---------------------------------------------------------------------------
// Slow (reg-staging) fp16 single-pass GEMM for the tiny proj matmul.
// ---------------------------------------------------------------------------
__device__ __forceinline__ ushort f2h_bits(float f) {
  _Float16 h = (_Float16)f;
  ushort u; __builtin_memcpy(&u, &h, 2); return u;
}

#define PK 40
template <int BM, int BN, int MF, int NF>
__global__ __launch_bounds__(256) void gemm_f32in(const float* __restrict__ A,
                                                  const float* __restrict__ W0,
                                                  const float* __restrict__ bias,
                                                  float* __restrict__ C,
                                                  int M, int K, int ldc) {
  __shared__ __attribute__((aligned(16))) ushort As[BM][PK];
  __shared__ __attribute__((aligned(16))) ushort Bs[BN][PK];
  constexpr int TPRA = 256 / BM;
  constexpr int EPTA = 32 / TPRA;
  constexpr int NA4  = EPTA / 4;
  constexpr int TPRB = 256 / BN;
  constexpr int EPTB = 32 / TPRB;
  constexpr int NB4  = EPTB / 4;

  int tid  = threadIdx.x;
  int lane = tid & 63, wid = tid >> 6;
  int wr = wid >> 1, wc = wid & 1;
  int lr = lane & 15, lk = lane >> 4;
  int bm = blockIdx.x, bn = blockIdx.y;

  int arow_s = tid / TPRA;
  int akoff  = (tid % TPRA) * EPTA;
  int ar = bm * BM + arow_s; if (ar >= M) ar = M - 1;
  const float* ap = A + (size_t)ar * K + akoff;

  int brow_s = tid / TPRB;
  int bkoff  = (tid % TPRB) * EPTB;
  int wrow   = bn * BN + brow_s;
  const float* wp = W0 + (size_t)wrow * K + bkoff;

  f32x4 acc[MF][NF] = {};

  float4 pa[NA4], pb[NB4];
#pragma unroll
  for (int u = 0; u < NA4; ++u) pa[u] = *(const float4*)(ap + u * 4);
#pragma unroll
  for (int u = 0; u < NB4; ++u) pb[u] = *(const float4*)(wp + u * 4);

  for (int k0 = 0; k0 < K; k0 += 32) {
#pragma unroll
    for (int u = 0; u < NA4; ++u) {
      ushort4 h;
      h.x = f2h_bits(pa[u].x);
      h.y = f2h_bits(pa[u].y);
      h.z = f2h_bits(pa[u].z);
      h.w = f2h_bits(pa[u].w);
      *(ushort4*)&As[arow_s][akoff + u * 4] = h;
    }
#pragma unroll
    for (int u = 0; u < NB4; ++u) {
      ushort4 h;
      h.x = f2h_bits(pb[u].x);
      h.y = f2h_bits(pb[u].y);
      h.z = f2h_bits(pb[u].z);
      h.w = f2h_bits(pb[u].w);
      *(ushort4*)&Bs[brow_s][bkoff + u * 4] = h;
    }
    __syncthreads();

    int kn = k0 + 32;
    if (kn < K) {
#pragma unroll
      for (int u = 0; u < NA4; ++u) pa[u] = *(const float4*)(ap + kn + u * 4);
#pragma unroll
      for (int u = 0; u < NB4; ++u) pb[u] = *(const float4*)(wp + kn + u * 4);
    }

    f16x8 af[MF], bf[NF];
#pragma unroll
    for (int m = 0; m < MF; ++m)
      af[m] = *(const f16x8*)&As[wr * (BM / 2) + m * 16 + lr][lk * 8];
#pragma unroll
    for (int n = 0; n < NF; ++n)
      bf[n] = *(const f16x8*)&Bs[wc * (BN / 2) + n * 16 + lr][lk * 8];
#pragma unroll
    for (int m = 0; m < MF; ++m)
#pragma unroll
      for (int n = 0; n < NF; ++n)
        acc[m][n] = __builtin_amdgcn_mfma_f32_16x16x32_f16(af[m], bf[n], acc[m][n], 0, 0, 0);
    __syncthreads();
  }

#pragma unroll
  for (int m = 0; m < MF; ++m) {
    int row0 = bm * BM + wr * (BM / 2) + m * 16 + lk * 4;
#pragma unroll
    for (int i = 0; i < 4; ++i) {
      int row = row0 + i;
      if (row < M) {
#pragma unroll
        for (int n = 0; n < NF; ++n) {
          int col = bn * BN + wc * (BN / 2) + n * 16 + lr;
          float vv = acc[m][n][i];
          if (bias) vv += bias[col];
          C[(size_t)row * ldc + col] = vv;
        }
      }
    }
  }
}

// ---------------------------------------------------------------------------
extern "C" void kernel_launch(void* const* d_in, const int* in_sizes, int n_in,
                              void* d_out, int out_size, void* d_ws, size_t ws_size,
                              hipStream_t stream) {
  const float* x      = (const float*)d_in[0];
  const float* attn   = (const float*)d_in[1];
  const float* q_w    = (const float*)d_in[2];
  const float* k_w    = (const float*)d_in[3];
  const float* v_w    = (const float*)d_in[4];
  const float* proj_w = (const float*)d_in[5];
  const float* proj_b = (const float*)d_in[6];
  float* out = (float*)d_out;

  char* w = (char*)d_ws;
  auto take = [&](size_t bytes) { char* p = w; w += (bytes + 255) & ~(size_t)255; return p; };
  float*  P     = (float*)take((size_t)L_ * B_ * N1_ * N1_ * 4);   // 59.6 MB
  float*  dvec  = (float*)take((size_t)L_ * B_ * N1_ * 4);
  int*    gidx  = (int*)take(B_ * R_ * 4);
  float*  qkv   = (float*)take((size_t)M_TOK * 2304 * 4);          // 58.1 MB
  float*  ctx   = (float*)take((size_t)B_ * R_ * D_ * 4);
  ushort* xpack = (ushort*)take((size_t)M_TOK * 768 * 2);          // 9.7 MB
  ushort* wpack = (ushort*)take((size_t)2304 * 768 * 2);           // 3.5 MB

  // 1) pack x and [k;v;q] to fp16 (GEMM input)
  hipLaunchKernelGGL(pack_fp16, dim3(PACK_BLOCKS), dim3(256), 0, stream,
                     x, k_w, v_w, q_w, xpack, wpack);
  // 2) MEGA: QKV GEMM (front-loaded 900 tiles, L3-resident MFMA) overlapped
  //    with k1 head-mean/normalize (HBM stream, 17344 blocks)
  hipLaunchKernelGGL(mega_gemm_k1, dim3(MEGA_BLOCKS), dim3(256), 0, stream,
                     xpack, wpack, qkv, attn, P, dvec);
  // 3) rollout chain (row 0) + top-19 (register-prefetched)
  hipLaunchKernelGGL(k2_chain_topk, dim3(B_), dim3(1024), 0, stream, P, dvec, gidx);
  // 4) attention per (b,h), q gathered from qkv
  hipLaunchKernelGGL(k5_attn, dim3(B_ * H_), dim3(256), 0, stream, qkv, gidx, ctx);
  // 5) output projection + bias -> d_out
  hipLaunchKernelGGL((gemm_f32in<64, 64, 2, 2>), dim3(10, 12), dim3(256), 0, stream,
                     ctx, proj_w, proj_b, out, B_ * R_, D_, D_);
}

// Round 11
// 314.309 us; speedup vs baseline: 1.1447x; 1.1447x over previous
//
#include <hip/hip_runtime.h>
#include <math.h>

#define L_  12
#define B_  32
#define H_  12
#define N1_ 197
#define D_  768
#define R_  19
#define M_TOK (B_ * N1_)               // 6304
#define NN (N1_ * N1_)                 // 38809

#define K1_FULL_ROWS  69344            // 11 layers * 32 b * 197 rows
#define K1_ROWS       69376            // + 32 layer-11 row-0 rows
#define K1_BLOCKS     (K1_ROWS / 4)    // 17344
#define PACK_ROWS     (M_TOK + 2304)   // x rows + [k;v;q] weight rows = 8608
#define PACK_BLOCKS   ((PACK_ROWS * 12 + 255) / 256)   // 404
#define QKV_TILES     630              // 600 KV tiles + 30 gathered-q tiles

typedef __attribute__((ext_vector_type(8))) _Float16 f16x8;
typedef __attribute__((ext_vector_type(4))) float f32x4;

__device__ __forceinline__ f32x4 ld4u(const float* p) {
  f32x4 r; __builtin_memcpy(&r, p, 16); return r;
}
__device__ __forceinline__ void st4u(float* p, f32x4 v) {
  __builtin_memcpy(p, &v, 16);
}
__device__ __forceinline__ ushort f2h_bits(float f) {
  _Float16 h = (_Float16)f;
  ushort u; __builtin_memcpy(&u, &h, 2); return u;
}
__device__ __forceinline__ float h2f(ushort u) {
  _Float16 h; __builtin_memcpy(&h, &u, 2); return (float)h;
}

typedef const __attribute__((address_space(1))) void* as1_vp;
typedef __attribute__((address_space(3))) void* as3_vp;
__device__ __forceinline__ void gl_lds16(const void* g, void* s) {
  __builtin_amdgcn_global_load_lds((as1_vp)g, (as3_vp)s, 16, 0, 0);
}

// ---------------------------------------------------------------------------
// MEGA1 (R9-proven, unchanged): k1 head-mean+normalize (one wave per row,
// float4-vectorized; layers 0..10 all rows, layer 11 row 0 only) + fp16 pack
// of x and [k_w;v_w;q_w] into [row][12][64 fp16 = 128B]. No LDS either side.
// ---------------------------------------------------------------------------
__global__ __launch_bounds__(256) void mega_k1_pack(const float* __restrict__ attn,
                                                    float* __restrict__ P,
                                                    float* __restrict__ dvec,
                                                    const float* __restrict__ x,
                                                    const float* __restrict__ k_w,
                                                    const float* __restrict__ v_w,
                                                    const float* __restrict__ q_w,
                                                    ushort* __restrict__ xpack,
                                                    ushort* __restrict__ wpack) {
  int bid = blockIdx.x;
  if (bid < K1_BLOCKS) {
    int wid = threadIdx.x >> 6;
    int t   = threadIdx.x & 63;
    int row_id = bid * 4 + wid;
    int l, b, i;
    if (row_id < K1_FULL_ROWS) {
      l = row_id / 6304;
      int rem = row_id - l * 6304;
      b = rem / 197;
      i = rem - b * 197;
    } else {
      l = 11; b = row_id - K1_FULL_ROWS; i = 0;
    }
    int lb   = l * B_ + b;
    int prow = lb * N1_ + i;
    const float* base = attn + (size_t)lb * (H_ * NN) + (size_t)i * N1_;
    f32x4 acc = {0.f, 0.f, 0.f, 0.f};
    if (t < 49) {
      const float* p = base + 4 * t;
#pragma unroll
      for (int h = 0; h < H_; ++h) acc += ld4u(p + (size_t)h * NN);
    } else if (t == 49) {
      const float* p = base + 196;
#pragma unroll
      for (int h = 0; h < H_; ++h) acc.x += p[(size_t)h * NN];
    }
    float s = (acc.x + acc.y) + (acc.z + acc.w);
#pragma unroll
    for (int o = 32; o; o >>= 1) s += __shfl_xor(s, o);
    float inv = 1.f / (s + 12.f);
    float* Pr = P + (size_t)prow * N1_;
    if (t < 49)       st4u(Pr + 4 * t, acc * inv);
    else if (t == 49) Pr[196] = acc.x * inv;
    if (t == 0) dvec[prow] = 12.f * inv;
  } else {
    int t = (bid - K1_BLOCKS) * 256 + threadIdx.x;
    if (t >= PACK_ROWS * 12) return;
    int row = t / 12, kb = t - row * 12;
    const float* src;
    ushort* dst;
    if (row < M_TOK) {
      src = x + (size_t)row * D_;
      dst = xpack + (size_t)row * 768;
    } else {
      int wr = row - M_TOK;                 // 0..2303
      int g = wr / 768, rl = wr - g * 768;
      const float* wsrc = (g == 0) ? k_w : (g == 1) ? v_w : q_w;
      src = wsrc + (size_t)rl * D_;
      dst = wpack + (size_t)wr * 768;
    }
    src += kb * 64;
    dst += kb * 64;
#pragma unroll
    for (int u = 0; u < 8; ++u) {
      float4 f = *(const float4*)(src + u * 8);
      float4 g = *(const float4*)(src + u * 8 + 4);
      f16x8 h;
      h[0] = (_Float16)f.x; h[1] = (_Float16)f.y;
      h[2] = (_Float16)f.z; h[3] = (_Float16)f.w;
      h[4] = (_Float16)g.x; h[5] = (_Float16)g.y;
      h[6] = (_Float16)g.z; h[7] = (_Float16)g.w;
      *(f16x8*)(dst + u * 8) = h;
    }
  }
}

// ---------------------------------------------------------------------------
// K2: rollout chain (row 0) + top-19. 1024 threads, 4-way i-split, register
// PREFETCH of next layer's P columns (v-independent loads -> L3 latency
// hidden under current layer's FMAs + barrier). [R10-verified correctness]
// ---------------------------------------------------------------------------
__global__ __launch_bounds__(1024) void k2_chain_topk(const float* __restrict__ P,
                                                      const float* __restrict__ dvec,
                                                      int* __restrict__ gidx) {
  int b = blockIdx.x;
  __shared__ float v[N1_];
  __shared__ float part[4][N1_];
  int t = threadIdx.x, quar = t >> 8, j = t & 255;
  int ibeg = (quar * N1_) / 4;              // 0,49,98,147
  bool last50 = (quar == 3);

  if (t < N1_) {
    const float* Pr = P + ((size_t)(11 * B_ + b) * N1_) * N1_;
    v[t] = Pr[t] + (t == 0 ? dvec[(11 * B_ + b) * N1_] : 0.f);
  }

  float cur[50], nxt[50];
  if (j < N1_) {
    const float* Pc = P + ((size_t)(10 * B_ + b) * N1_) * N1_ + j;
#pragma unroll
    for (int u = 0; u < 50; ++u) {
      int i = ibeg + u; if (i > 196) i = 196;
      cur[u] = Pc[(size_t)i * N1_];
    }
  }
  __syncthreads();

  for (int l = 10; l >= 0; --l) {
    if (l > 0 && j < N1_) {                 // prefetch layer l-1
      const float* Pc = P + ((size_t)((l - 1) * B_ + b) * N1_) * N1_ + j;
#pragma unroll
      for (int u = 0; u < 50; ++u) {
        int i = ibeg + u; if (i > 196) i = 196;
        nxt[u] = Pc[(size_t)i * N1_];
      }
    }
    if (j < N1_) {
      float a0 = 0.f, a1 = 0.f, a2 = 0.f, a3 = 0.f;
#pragma unroll
      for (int u = 0; u < 48; u += 4) {
        a0 += v[ibeg + u]     * cur[u];
        a1 += v[ibeg + u + 1] * cur[u + 1];
        a2 += v[ibeg + u + 2] * cur[u + 2];
        a3 += v[ibeg + u + 3] * cur[u + 3];
      }
      a0 += v[ibeg + 48] * cur[48];
      if (last50) a1 += v[ibeg + 49] * cur[49];
      float s = (a0 + a1) + (a2 + a3);
      if (quar == 0) s += v[j] * dvec[(l * B_ + b) * N1_ + j];   // diagonal
      part[quar][j] = s;
    }
    __syncthreads();
    if (t < N1_) v[t] = (part[0][t] + part[1][t]) + (part[2][t] + part[3][t]);
    __syncthreads();
#pragma unroll
    for (int u = 0; u < 50; ++u) cur[u] = nxt[u];
  }

  // top-19 over v[1..196]; jax tie-break: value desc, index asc
  if (t < 64) {
    float val[4];
    int   idx[4];
#pragma unroll
    for (int c = 0; c < 4; ++c) {
      int n = t + c * 64;
      bool ok = (n < N1_ - 1);
      val[c] = ok ? v[n + 1] : -1e30f;
      idx[c] = ok ? n : (1 << 20);
    }
    for (int r = 0; r < R_; ++r) {
      float bv = val[0];
      int   bi = idx[0];
#pragma unroll
      for (int c = 1; c < 4; ++c)
        if (val[c] > bv || (val[c] == bv && idx[c] < bi)) { bv = val[c]; bi = idx[c]; }
#pragma unroll
      for (int o = 32; o; o >>= 1) {
        float ov = __shfl_xor(bv, o);
        int   oi = __shfl_xor(bi, o);
        if (ov > bv || (ov == bv && oi < bi)) { bv = ov; bi = oi; }
      }
      if (t == 0) gidx[b * R_ + r] = b * N1_ + bi + 1;
#pragma unroll
      for (int c = 0; c < 4; ++c)
        if (idx[c] == bi) val[c] = -1e30f;
    }
  }
}

// ---------------------------------------------------------------------------
// FAST fp16 GEMM (R9-proven), fused KV (600 tiles) + gathered-q (30 tiles).
// NEW: C outputs stored as fp16 (halves write traffic; downstream attn is
// fp16-tolerant). Staging/swizzle identical to R9.
// ---------------------------------------------------------------------------
__global__ __launch_bounds__(256) void gemm_kvq_fast(const ushort* __restrict__ xpack,
                                                     const ushort* __restrict__ wpack,
                                                     const int* __restrict__ gidx,
                                                     ushort* __restrict__ kvb,
                                                     ushort* __restrict__ qbuf) {
  __shared__ __attribute__((aligned(16))) ushort As[128 * 64];
  __shared__ __attribute__((aligned(16))) ushort Bs[128 * 64];
  int tid = threadIdx.x, lane = tid & 63, wid = tid >> 6;
  int wr = wid >> 1, wc = wid & 1;
  int lr = lane & 15, lk = lane >> 4;

  int bid = blockIdx.x;
  int bm, wrow0, ccol0, ldc, Mrows;
  ushort* C;
  bool gath;
  if (bid < 600) {
    bm = bid % 50; int bn = bid / 50;
    wrow0 = bn * 128; ccol0 = bn * 128; ldc = 1536; Mrows = M_TOK;
    C = kvb; gath = false;
  } else {
    int tq = bid - 600;
    bm = tq % 5; int bn = tq / 5;
    wrow0 = 1536 + bn * 128; ccol0 = bn * 128; ldc = 768; Mrows = 608;
    C = qbuf; gath = true;
  }

  const ushort* asrc[4];
  const ushort* bsrc[4];
  ushort* adst[4];
  ushort* bdst[4];
  int lrow = lane >> 3, cpr = lane & 7;
#pragma unroll
  for (int i = 0; i < 4; ++i) {
    int r_loc = wid * 32 + i * 8 + lrow;
    int c     = cpr ^ (r_loc & 7);
    int ga    = bm * 128 + r_loc; if (ga >= Mrows) ga = Mrows - 1;
    int arow  = gath ? gidx[ga] : ga;
    asrc[i] = xpack + (size_t)arow * 768 + c * 8;
    bsrc[i] = wpack + (size_t)(wrow0 + r_loc) * 768 + c * 8;
    adst[i] = &As[(wid * 32 + i * 8) * 64];
    bdst[i] = &Bs[(wid * 32 + i * 8) * 64];
  }

  int o0 = (lk ^ (lr & 7)) * 8;      // slice 0 (k 0..31)
  int o1 = o0 ^ 32;                  // slice 1 (k 32..63)

  f32x4 acc[4][4] = {};

#pragma unroll
  for (int i = 0; i < 4; ++i) { gl_lds16(asrc[i], adst[i]); gl_lds16(bsrc[i], bdst[i]); }

  for (int kb = 0; kb < 12; ++kb) {
    __syncthreads();
    f16x8 af0[4], af1[4], bf0[4], bf1[4];
#pragma unroll
    for (int m = 0; m < 4; ++m) {
      const ushort* rp = &As[(wr * 64 + m * 16 + lr) * 64];
      af0[m] = *(const f16x8*)(rp + o0);
      af1[m] = *(const f16x8*)(rp + o1);
    }
#pragma unroll
    for (int n = 0; n < 4; ++n) {
      const ushort* rp = &Bs[(wc * 64 + n * 16 + lr) * 64];
      bf0[n] = *(const f16x8*)(rp + o0);
      bf1[n] = *(const f16x8*)(rp + o1);
    }
    __syncthreads();
    if (kb < 11) {
#pragma unroll
      for (int i = 0; i < 4; ++i) {
        gl_lds16(asrc[i] + (kb + 1) * 64, adst[i]);
        gl_lds16(bsrc[i] + (kb + 1) * 64, bdst[i]);
      }
    }
#pragma unroll
    for (int m = 0; m < 4; ++m)
#pragma unroll
      for (int n = 0; n < 4; ++n) {
        acc[m][n] = __builtin_amdgcn_mfma_f32_16x16x32_f16(af0[m], bf0[n], acc[m][n], 0, 0, 0);
        acc[m][n] = __builtin_amdgcn_mfma_f32_16x16x32_f16(af1[m], bf1[n], acc[m][n], 0, 0, 0);
      }
  }

#pragma unroll
  for (int m = 0; m < 4; ++m) {
    int row0 = bm * 128 + wr * 64 + m * 16 + (lane >> 4) * 4;
#pragma unroll
    for (int i = 0; i < 4; ++i) {
      int row = row0 + i;
      if (row < Mrows) {
#pragma unroll
        for (int n = 0; n < 4; ++n) {
          int col = ccol0 + wc * 64 + n * 16 + lr;
          C[(size_t)row * ldc + col] = f2h_bits(acc[m][n][i]);
        }
      }
    }
  }
}

// ---------------------------------------------------------------------------
// K5: per-(b,h) attention. fp16 K/V/q inputs (f32 compute). NEW: after QK^T,
// K's LDS region is dead -> stage V into it (coalesced, pipelined) and run
// PV from LDS (lane-consecutive reads, conflict-free) instead of chaining
// 197 strided-6KB global loads.
// ---------------------------------------------------------------------------
__global__ __launch_bounds__(256) void k5_attn(const ushort* __restrict__ kvb,
                                               const ushort* __restrict__ qb,
                                               float* __restrict__ ctx) {
  int bh = blockIdx.x;
  int b = bh / H_, h = bh % H_;
  __shared__ float ks[N1_][68];     // K for phase1, then reused as V
  __shared__ float qs[R_][64];
  __shared__ float sc[R_][200];
  __shared__ float rsum[R_];
  int t = threadIdx.x;
  int lane = t & 63, wid = t >> 6;

  const ushort* kb16 = kvb + (size_t)b * N1_ * 1536 + h * 64;
  for (int n = wid; n < N1_; n += 4)
    ks[n][lane] = h2f(kb16[(size_t)n * 1536 + lane]);
  const ushort* qb16 = qb + (size_t)(b * R_) * 768 + h * 64;
  for (int e = t; e < R_ * 64; e += 256) {
    int r = e >> 6, d = e & 63;
    qs[r][d] = h2f(qb16[(size_t)r * 768 + d]);
  }
  __syncthreads();

  // phase 1: thread t = key n; S[r][n] = 0.125 * q[r].k[n]
  if (t < N1_) {
    float accr[R_];
#pragma unroll
    for (int r = 0; r < R_; ++r) accr[r] = 0.f;
#pragma unroll
    for (int d0 = 0; d0 < 4; ++d0) {
      float4 k0 = *(const float4*)&ks[t][d0 * 16 + 0];
      float4 k1 = *(const float4*)&ks[t][d0 * 16 + 4];
      float4 k2 = *(const float4*)&ks[t][d0 * 16 + 8];
      float4 k3 = *(const float4*)&ks[t][d0 * 16 + 12];
#pragma unroll
      for (int r = 0; r < R_; ++r) {
        float4 q0 = *(const float4*)&qs[r][d0 * 16 + 0];
        float4 q1 = *(const float4*)&qs[r][d0 * 16 + 4];
        float4 q2 = *(const float4*)&qs[r][d0 * 16 + 8];
        float4 q3 = *(const float4*)&qs[r][d0 * 16 + 12];
        accr[r] += k0.x * q0.x + k0.y * q0.y + k0.z * q0.z + k0.w * q0.w
                 + k1.x * q1.x + k1.y * q1.y + k1.z * q1.z + k1.w * q1.w
                 + k2.x * q2.x + k2.y * q2.y + k2.z * q2.z + k2.w * q2.w
                 + k3.x * q3.x + k3.y * q3.y + k3.z * q3.z + k3.w * q3.w;
      }
    }
#pragma unroll
    for (int r = 0; r < R_; ++r) sc[r][t] = accr[r] * 0.125f;
  }
  __syncthreads();

  // stage V into the dead K region (disjoint from sc/rsum work below)
  const ushort* vb16 = kvb + (size_t)b * N1_ * 1536 + 768 + h * 64;
  for (int n = wid; n < N1_; n += 4)
    ks[n][lane] = h2f(vb16[(size_t)n * 1536 + lane]);

  // softmax over n for rows r = wid, wid+4, ...
  for (int r = wid; r < R_; r += 4) {
    float x0 = sc[r][lane];
    float x1 = sc[r][lane + 64];
    float x2 = sc[r][lane + 128];
    bool ok3 = (lane + 192 < N1_);
    float x3 = ok3 ? sc[r][lane + 192] : -1e30f;
    float m = fmaxf(fmaxf(x0, x1), fmaxf(x2, x3));
#pragma unroll
    for (int o = 32; o; o >>= 1) m = fmaxf(m, __shfl_xor(m, o));
    float e0 = expf(x0 - m), e1 = expf(x1 - m), e2 = expf(x2 - m);
    float e3 = ok3 ? expf(x3 - m) : 0.f;
    float s = e0 + e1 + e2 + e3;
#pragma unroll
    for (int o = 32; o; o >>= 1) s += __shfl_xor(s, o);
    sc[r][lane] = e0; sc[r][lane + 64] = e1; sc[r][lane + 128] = e2;
    if (ok3) sc[r][lane + 192] = e3;
    if (lane == 0) rsum[r] = s;
  }
  __syncthreads();

  // PV from LDS: thread (wid, lane=d), rows r = wid + 4k
  int r0 = wid, r1 = wid + 4, r2 = wid + 8, r3 = wid + 12, r4 = wid + 16;
  bool has4 = (r4 < R_);
  float a0 = 0.f, a1 = 0.f, a2 = 0.f, a3 = 0.f, a4 = 0.f;
#pragma unroll 4
  for (int n = 0; n < N1_; ++n) {
    float vv = ks[n][lane];
    a0 += sc[r0][n] * vv;
    a1 += sc[r1][n] * vv;
    a2 += sc[r2][n] * vv;
    a3 += sc[r3][n] * vv;
    if (has4) a4 += sc[r4][n] * vv;
  }
  float* cb = ctx + (size_t)(b * R_) * D_ + h * 64 + lane;
  cb[(size_t)r0 * D_] = a0 / rsum[r0];
  cb[(size_t)r1 * D_] = a1 / rsum[r1];
  cb[(size_t)r2 * D_] = a2 / rsum[r2];
  cb[(size_t)r3 * D_] = a3 / rsum[r3];
  if (has4) cb[(size_t)r4 * D_] = a4 / rsum[r4];
}

// ---------------------------------------------------------------------------
// Slow (reg-staging) fp16 single-pass GEMM for the tiny proj matmul.
// ---------------------------------------------------------------------------
#define PK 40
template <int BM, int BN, int MF, int NF>
__global__ __launch_bounds__(256) void gemm_f32in(const float* __restrict__ A,
                                                  const float* __restrict__ W0,
                                                  const float* __restrict__ bias,
                                                  float* __restrict__ C,
                                                  int M, int K, int ldc) {
  __shared__ __attribute__((aligned(16))) ushort As[BM][PK];
  __shared__ __attribute__((aligned(16))) ushort Bs[BN][PK];
  constexpr int TPRA = 256 / BM;
  constexpr int EPTA = 32 / TPRA;
  constexpr int NA4  = EPTA / 4;
  constexpr int TPRB = 256 / BN;
  constexpr int EPTB = 32 / TPRB;
  constexpr int NB4  = EPTB / 4;

  int tid  = threadIdx.x;
  int lane = tid & 63, wid = tid >> 6;
  int wr = wid >> 1, wc = wid & 1;
  int lr = lane & 15, lk = lane >> 4;
  int bm = blockIdx.x, bn = blockIdx.y;

  int arow_s = tid / TPRA;
  int akoff  = (tid % TPRA) * EPTA;
  int ar = bm * BM + arow_s; if (ar >= M) ar = M - 1;
  const float* ap = A + (size_t)ar * K + akoff;

  int brow_s = tid / TPRB;
  int bkoff  = (tid % TPRB) * EPTB;
  int wrow   = bn * BN + brow_s;
  const float* wp = W0 + (size_t)wrow * K + bkoff;

  f32x4 acc[MF][NF] = {};

  float4 pa[NA4], pb[NB4];
#pragma unroll
  for (int u = 0; u < NA4; ++u) pa[u] = *(const float4*)(ap + u * 4);
#pragma unroll
  for (int u = 0; u < NB4; ++u) pb[u] = *(const float4*)(wp + u * 4);

  for (int k0 = 0; k0 < K; k0 += 32) {
#pragma unroll
    for (int u = 0; u < NA4; ++u) {
      ushort4 h;
      h.x = f2h_bits(pa[u].x);
      h.y = f2h_bits(pa[u].y);
      h.z = f2h_bits(pa[u].z);
      h.w = f2h_bits(pa[u].w);
      *(ushort4*)&As[arow_s][akoff + u * 4] = h;
    }
#pragma unroll
    for (int u = 0; u < NB4; ++u) {
      ushort4 h;
      h.x = f2h_bits(pb[u].x);
      h.y = f2h_bits(pb[u].y);
      h.z = f2h_bits(pb[u].z);
      h.w = f2h_bits(pb[u].w);
      *(ushort4*)&Bs[brow_s][bkoff + u * 4] = h;
    }
    __syncthreads();

    int kn = k0 + 32;
    if (kn < K) {
#pragma unroll
      for (int u = 0; u < NA4; ++u) pa[u] = *(const float4*)(ap + kn + u * 4);
#pragma unroll
      for (int u = 0; u < NB4; ++u) pb[u] = *(const float4*)(wp + kn + u * 4);
    }

    f16x8 af[MF], bf[NF];
#pragma unroll
    for (int m = 0; m < MF; ++m)
      af[m] = *(const f16x8*)&As[wr * (BM / 2) + m * 16 + lr][lk * 8];
#pragma unroll
    for (int n = 0; n < NF; ++n)
      bf[n] = *(const f16x8*)&Bs[wc * (BN / 2) + n * 16 + lr][lk * 8];
#pragma unroll
    for (int m = 0; m < MF; ++m)
#pragma unroll
      for (int n = 0; n < NF; ++n)
        acc[m][n] = __builtin_amdgcn_mfma_f32_16x16x32_f16(af[m], bf[n], acc[m][n], 0, 0, 0);
    __syncthreads();
  }

#pragma unroll
  for (int m = 0; m < MF; ++m) {
    int row0 = bm * BM + wr * (BM / 2) + m * 16 + lk * 4;
#pragma unroll
    for (int i = 0; i < 4; ++i) {
      int row = row0 + i;
      if (row < M) {
#pragma unroll
        for (int n = 0; n < NF; ++n) {
          int col = bn * BN + wc * (BN / 2) + n * 16 + lr;
          float vv = acc[m][n][i];
          if (bias) vv += bias[col];
          C[(size_t)row * ldc + col] = vv;
        }
      }
    }
  }
}

// ---------------------------------------------------------------------------
extern "C" void kernel_launch(void* const* d_in, const int* in_sizes, int n_in,
                              void* d_out, int out_size, void* d_ws, size_t ws_size,
                              hipStream_t stream) {
  const float* x      = (const float*)d_in[0];
  const float* attn   = (const float*)d_in[1];
  const float* q_w    = (const float*)d_in[2];
  const float* k_w    = (const float*)d_in[3];
  const float* v_w    = (const float*)d_in[4];
  const float* proj_w = (const float*)d_in[5];
  const float* proj_b = (const float*)d_in[6];
  float* out = (float*)d_out;

  char* w = (char*)d_ws;
  auto take = [&](size_t bytes) { char* p = w; w += (bytes + 255) & ~(size_t)255; return p; };
  float*  P     = (float*)take((size_t)L_ * B_ * N1_ * N1_ * 4);   // 59.6 MB
  float*  dvec  = (float*)take((size_t)L_ * B_ * N1_ * 4);
  int*    gidx  = (int*)take(B_ * R_ * 4);
  ushort* kvb   = (ushort*)take((size_t)M_TOK * 1536 * 2);         // 19.4 MB fp16
  ushort* qbuf  = (ushort*)take((size_t)B_ * R_ * D_ * 2);         // fp16
  float*  ctx   = (float*)take((size_t)B_ * R_ * D_ * 4);
  ushort* xpack = (ushort*)take((size_t)M_TOK * 768 * 2);          // 9.7 MB
  ushort* wpack = (ushort*)take((size_t)2304 * 768 * 2);           // 3.5 MB

  // 1) MEGA1: vectorized k1 (HBM stream) + fp16 packing (no LDS either side)
  hipLaunchKernelGGL(mega_k1_pack, dim3(K1_BLOCKS + PACK_BLOCKS), dim3(256), 0,
                     stream, attn, P, dvec, x, k_w, v_w, q_w, xpack, wpack);
  // 2) rollout chain (row 0) + top-19 indices (register-prefetched)
  hipLaunchKernelGGL(k2_chain_topk, dim3(B_), dim3(1024), 0, stream, P, dvec, gidx);
  // 3) fused fast fp16 GEMM: KV (600 tiles) + gathered-q (30 tiles), fp16 out
  hipLaunchKernelGGL(gemm_kvq_fast, dim3(QKV_TILES), dim3(256), 0, stream,
                     xpack, wpack, gidx, kvb, qbuf);
  // 4) attention per (b,h), V staged via LDS
  hipLaunchKernelGGL(k5_attn, dim3(B_ * H_), dim3(256), 0, stream, kvb, qbuf, ctx);
  // 5) output projection + bias -> d_out
  hipLaunchKernelGGL((gemm_f32in<64, 64, 2, 2>), dim3(10, 12), dim3(256), 0, stream,
                     ctx, proj_w, proj_b, out, B_ * R_, D_, D_);
}